// Round 1
// baseline (776.036 us; speedup 1.0000x reference)
//
#include <hip/hip_runtime.h>

#define ENTITIES_N 100000
#define RELATIONS_N 1000
#define WIDTH (2 * ENTITIES_N + RELATIONS_N)   // 201000
#define BATCH_ROWS 1024                        // fixed by the problem (BATCH = 1024)

// Structure: graph memset node zeroes EXACTLY the 823 MB output (prior version
// memset 4x that — rocprof WRITE_SIZE showed 3,216,000 KB vs the logical
// 804,000 KB, proving out_size is a BYTE count). Then a tiny scatter kernel
// writes the 3*1024 ones. h/r/t column segments are disjoint -> no conflicts.
__global__ void scatter_ones_i32(const int* __restrict__ hID,
                                 const int* __restrict__ rID,
                                 const int* __restrict__ tID,
                                 float* __restrict__ out, int batch) {
    int row = blockIdx.x * blockDim.x + threadIdx.x;
    if (row >= batch) return;
    long long base = (long long)row * WIDTH;
    out[base + (long long)hID[row]] = 1.0f;
    out[base + ENTITIES_N + (long long)rID[row]] = 1.0f;
    out[base + ENTITIES_N + RELATIONS_N + (long long)tID[row]] = 1.0f;
}

__global__ void scatter_ones_i64(const long long* __restrict__ hID,
                                 const int* __restrict__ rID,
                                 const int* __restrict__ tID,
                                 float* __restrict__ out, int batch) {
    int row = blockIdx.x * blockDim.x + threadIdx.x;
    if (row >= batch) return;
    long long base = (long long)row * WIDTH;
    out[base + hID[row]] = 1.0f;
    out[base + ENTITIES_N + (long long)rID[row]] = 1.0f;
    out[base + ENTITIES_N + RELATIONS_N + (long long)tID[row]] = 1.0f;
}

extern "C" void kernel_launch(void* const* d_in, const int* in_sizes, int n_in,
                              void* d_out, int out_size, void* d_ws, size_t ws_size,
                              hipStream_t stream) {
    // Inputs (setup_inputs order): z [B,128] f32 (unused), hID [B] int32/int64,
    // rID [B] i32, tID [B] i32.
    const int* rID = (const int*)d_in[2];
    const int* tID = (const int*)d_in[3];
    float* out = (float*)d_out;

    // Sizes are compile-time-known from the problem spec; hard-coding makes us
    // immune to the bytes-vs-elements convention of out_size/in_sizes.
    const int batch = BATCH_ROWS;
    const size_t out_bytes = (size_t)batch * WIDTH * sizeof(float);  // 823,296,000 B

    // Zero exactly the output. Captured memset node runs at ~6.34 TB/s
    // (rocprof: fill dispatch at 79% of 8 TB/s spec = write ceiling).
    hipMemsetAsync(d_out, 0, out_bytes, stream);

    const int block = 256;
    const int grid = (batch + block - 1) / block;  // 4 workgroups
    // hID is i64 iff its size is 2x tID's (same element count, tID always i32).
    // This ratio test works whether in_sizes[] is in bytes or elements.
    if (in_sizes[1] == 2 * in_sizes[3]) {
        scatter_ones_i64<<<grid, block, 0, stream>>>((const long long*)d_in[1], rID, tID, out, batch);
    } else {
        scatter_ones_i32<<<grid, block, 0, stream>>>((const int*)d_in[1], rID, tID, out, batch);
    }
}